// Round 15
// baseline (170.571 us; speedup 1.0000x reference)
//
#include <hip/hip_runtime.h>
#include <hip/hip_bf16.h>

// GLM flash attention fwd: b=2, s=2048, nh=16, hs=64, fp32 I/O, bf16 MFMA.
// R21 (resubmit; prior run failed at container level, no signal).
// 4 independent waves/SIMD. R20 (fragment-tiled loads, 24 seg/chunk)
// fixed the request-rate wall: MfmaUtil 21% + VALUBusy 31%, ~48% idle at
// ~2 waves/SIMD (grid-limited). Halve tile to 16 q-rows -> 4096 one-wave
// blocks = 4 waves/SIMD. R13's squeeze cannot recur: all K/V loads are
// volatile asm with forced-live destinations (~110 VGPR floor). Single
// carried K buffer (WAR-safe: loads issue after the MFMAs that read the
// old value) keeps demand ~125 <= 128. launch_bounds(64,3): no forced
// spill; 4 waves if allocator lands <=128. Everything else = R20 (passed):
// fragment-tiled kbuf/vbuf from conv_kv, swapped QK^T -> P in registers in
// MFMA16 A-layout -> PV direct, zero LDS, zero barriers, counted
// vmcnt(16)/vmcnt(8), no split-K, no atomics, in-register normalize.

typedef __attribute__((ext_vector_type(8))) __bf16 bf16x8;
typedef __attribute__((ext_vector_type(4))) __bf16 bf16x4;
typedef __attribute__((ext_vector_type(4))) float floatx4;
typedef __attribute__((ext_vector_type(2))) float f32x2;
typedef __attribute__((ext_vector_type(4))) short s16x4;

#define S_LEN 2048
#define NH 16
#define HS 64
#define RS 1024                     // fp32 floats between seq positions
#define KB_ELEMS (2 * NH * S_LEN * HS)   // 4,194,304 bf16 = 8 MB
#define BH_ELEMS (S_LEN * HS)            // 131072 bf16 per (b,h)
#define SCALE_LOG2E 0.18033688011112042f // 0.125 / ln(2)

#if __has_builtin(__builtin_amdgcn_exp2f)
#define EXP2(x) __builtin_amdgcn_exp2f(x)
#else
#define EXP2(x) exp2f(x)
#endif

#define MFMA(a, b, c) __builtin_amdgcn_mfma_f32_16x16x32_bf16(a, b, c, 0, 0, 0)
// v_mfma_f32_16x16x16_bf16: A/B = 2 VGPRs (4 bf16 as v4i16), C/D = 4 VGPRs
#define MFMA16(a, b, c) __builtin_amdgcn_mfma_f32_16x16x16bf16_1k(a, b, c, 0, 0, 0)

// ---- pre-pass: K -> A-frag tiles (scaled), V -> MFMA16-B-frag tiles ----
// (byte-identical to R20, which passed)
// kbuf, per (b,h): tile (kb in [0,128), hf in [0,2)) of 1KB at offset
//   ((kb*2+hf)*512 + l*8) elems; slot l (= quad*16+col) holds 8 bf16:
//   K[kb*16+col][hf*32+quad*8+j] * SCALE_LOG2E.
// vbuf, per (b,h): tile (kb, f in [0,4)) of 512B at offset
//   ((kb*4+f)*256 + l*4) elems; slot l holds 4 bf16:
//   V[kb*16+(l>>4)*4+j][f*16+(l&15)].
__global__ __launch_bounds__(256) void conv_kv(const float* __restrict__ k,
                                               const float* __restrict__ v,
                                               __bf16* __restrict__ kbuf,
                                               __bf16* __restrict__ vbuf)
{
    __shared__ __align__(16) __bf16 tile[64][72];     // [d][s], 144B rows
    const int tid = threadIdx.x;

    const int bh = blockIdx.x >> 5;                   // 32 s-tiles per (b,h)
    const int st = blockIdx.x & 31;
    const int b = bh >> 4, h = bh & 15;
    const int s0 = st * 64;
    const int kb0 = st * 4;                           // base 16-k block

    __bf16* kout = kbuf + (size_t)(b * 16 + h) * BH_ELEMS;
    __bf16* vout = vbuf + (size_t)(b * 16 + h) * BH_ELEMS;

    // K: read coalesced (32B/thread along rows), write A-frag slots
#pragma unroll
    for (int it = 0; it < 2; ++it) {
        const int idx = it * 256 + tid;               // 0..511
        const int sl = idx >> 3;                      // local k row 0..63
        const int g  = idx & 7;                       // 8-float d-granule
        const float* kp = k + ((size_t)(b * 2048 + s0 + sl)) * 1024 + h * 64 + g * 8;
        floatx4 v0 = *(const floatx4*)kp;
        floatx4 v1 = *(const floatx4*)(kp + 4);
        bf16x8 w;
#pragma unroll
        for (int i = 0; i < 4; ++i) {
            w[i]     = (__bf16)(v0[i] * SCALE_LOG2E);
            w[4 + i] = (__bf16)(v1[i] * SCALE_LOG2E);
        }
        const int kb = kb0 + (sl >> 4);
        const int l  = (g & 3) * 16 + (sl & 15);      // quad=g&3, col=sl&15
        *(bf16x8*)(kout + ((kb * 2 + (g >> 2)) * 512 + l * 8)) = w;
    }

    // V: build [d][s] transpose in LDS (as before)
#pragma unroll
    for (int it = 0; it < 4; ++it) {
        const int idx = it * 256 + tid;
        const int s = idx >> 4, f4 = idx & 15;
        floatx4 val = *(const floatx4*)(v + ((size_t)(b * 2048 + s0 + s)) * 1024 + h * 64 + f4 * 4);
#pragma unroll
        for (int i = 0; i < 4; ++i)
            tile[f4 * 4 + i][s] = (__bf16)val[i];
    }
    __syncthreads();

    // emit B-frag slots (8B/thread, writes fully coalesced per tile)
#pragma unroll
    for (int it = 0; it < 4; ++it) {
        const int idx = it * 256 + tid;               // 0..1023
        const int kbl = idx >> 8;                     // 0..3
        const int f   = (idx >> 6) & 3;
        const int l   = idx & 63;
        const int col = l & 15, q4 = l >> 4;
        bf16x4 w = *(const bf16x4*)&tile[f * 16 + col][kbl * 16 + q4 * 4];
        *(bf16x4*)(vout + (((kb0 + kbl) * 4 + f) * 256 + l * 4)) = w;
    }
}

// ---- main kernel: 1 wave/block, 16 q-rows, all-register, 4 waves/SIMD ----
__global__ __launch_bounds__(64, 3) void fa_part16(
    const float* __restrict__ q, const __bf16* __restrict__ kb,
    const __bf16* __restrict__ vt, const int* __restrict__ glm_mask,
    float* __restrict__ out)
{
    const int lane = threadIdx.x;                 // one wave per block
    const int col  = lane & 15, quad = lane >> 4;

    // LPT order: longest q-tiles first (q0 descending), heads fastest
    const int tile = blockIdx.x >> 5;             // 0..127
    const int head = blockIdx.x & 31;
    const int b = head >> 4, h = head & 15;
    const int q0 = (127 - tile) * 16;             // this wave's 16 q-rows

    const int bp = glm_mask[b];
    int klen = q0 + 16; if (bp > klen) klen = bp;
    const int nch = (klen + 63) >> 6;             // 1..32

    const __bf16* kbh = kb + (size_t)(b * 16 + h) * BH_ELEMS;
    const __bf16* vth = vt + (size_t)(b * 16 + h) * BH_ELEMS;
    const size_t obase = (size_t)b * (S_LEN * RS) + h * HS;

    // per-lane slot bases (fully coalesced: lane-linear)
    const char* klp = (const char*)kbh + lane * 16;
    const char* vlp = (const char*)vth + lane * 8;

// K(c) -> bk (8 x 16B volatile asm loads, each ONE 1KB segment)
#define LOADK(K0)                                                              \
  _Pragma("unroll")                                                            \
  for (int kg = 0; kg < 4; ++kg)                                               \
    _Pragma("unroll")                                                          \
    for (int hf = 0; hf < 2; ++hf) {                                           \
      unsigned long long ka = (unsigned long long)(klp +                       \
          (size_t)(K0) * 128 + kg * 2048 + hf * 1024);                         \
      __asm__ __volatile__("global_load_dwordx4 %0, %1, off"                   \
                           : "=v"(bk[kg][hf]) : "v"(ka) : "memory");           \
    }

// V(c) -> bv (16 x 8B volatile asm loads, each ONE 512B segment)
#define LOADV(K0)                                                              \
  _Pragma("unroll")                                                            \
  for (int kg = 0; kg < 4; ++kg)                                               \
    _Pragma("unroll")                                                          \
    for (int f = 0; f < 4; ++f) {                                              \
      unsigned long long va = (unsigned long long)(vlp +                       \
          (size_t)(K0) * 128 + kg * 2048 + f * 512);                           \
      __asm__ __volatile__("global_load_dwordx2 %0, %1, off"                   \
                           : "=v"(bv[f][kg]) : "v"(va) : "memory");            \
    }

    // Q B-frag: aq[half], lane holds Q[q=q0+col][d=half*32+quad*8+j]
    bf16x8 aq[2];
    {
        const float* qp = q + obase + (size_t)(q0 + col) * RS + quad * 8;
        floatx4 a0 = *(const floatx4*)qp;
        floatx4 a1 = *(const floatx4*)(qp + 4);
        floatx4 a2 = *(const floatx4*)(qp + 32);
        floatx4 a3 = *(const floatx4*)(qp + 36);
#pragma unroll
        for (int i = 0; i < 4; ++i) {
            aq[0][i] = (__bf16)a0[i]; aq[0][4 + i] = (__bf16)a1[i];
            aq[1][i] = (__bf16)a2[i]; aq[1][4 + i] = (__bf16)a3[i];
        }
    }

    floatx4 o[4];                   // O C-frags: row = q0+quad*4+r, d = f*16+col
    float ls = 0.f;                 // per-lane l partial for q = q0+col
#pragma unroll
    for (int f = 0; f < 4; ++f) o[f] = (floatx4){0.f, 0.f, 0.f, 0.f};

    bf16x8 bk[4][2];                // single carried K buffer
    f32x2 bv[4][4];

    LOADK(0);                       // prologue: K(0) in flight (8 vm ops)

    for (int c = 0; c < nch; ++c) {
        const int k0 = c * 64;

        LOADV(k0);        // 16 V ops enqueued behind the 8 K(c) ops
        // drain the 8 oldest (K(c)); 16 V stay in flight
        __asm__ __volatile__("s_waitcnt vmcnt(16)" ::: "memory");
        __builtin_amdgcn_sched_barrier(0);

        // QK^T swapped: S^T = K . Q^T -> lane holds P[q=col][k=kg*16+quad*4+r]
        floatx4 z = {0.f, 0.f, 0.f, 0.f};
        floatx4 s[4];
        __builtin_amdgcn_s_setprio(1);
#pragma unroll
        for (int kg = 0; kg < 4; ++kg) {
            s[kg] = MFMA(bk[kg][0], aq[0], z);
            s[kg] = MFMA(bk[kg][1], aq[1], s[kg]);
        }
        __builtin_amdgcn_s_setprio(0);

        // prefetch K(c+1) into the SAME buffer (WAR-safe: issued after the
        // MFMAs consumed the old values; in-order issue per wave)
        if (c + 1 < nch) { LOADK(k0 + 64); }

        // exp + mask + pack to MFMA16 A-frags (all in registers)
        const bool full = (k0 + 63 < bp) || (k0 + 63 <= q0);
        const int qi = q0 + col;
        s16x4 pa[4];
#pragma unroll
        for (int kg = 0; kg < 4; ++kg) {
            bf16x4 pv4;
#pragma unroll
            for (int r = 0; r < 4; ++r) {
                float e = EXP2(s[kg][r]);
                if (!full) {
                    const int kj = k0 + kg * 16 + quad * 4 + r;
                    if (!((kj < bp) || (kj <= qi))) e = 0.f;
                }
                ls += e;
                pv4[r] = (__bf16)e;
            }
            pa[kg] = __builtin_bit_cast(s16x4, pv4);
        }

        // drain V(c); K(c+1) stays in flight (counted)
        if (c + 1 < nch) {
            __asm__ __volatile__("s_waitcnt vmcnt(8)" ::: "memory");
        } else {
            __asm__ __volatile__("s_waitcnt vmcnt(0)" ::: "memory");
        }
        __builtin_amdgcn_sched_barrier(0);  // rule #18: PV stays behind wait

        // PV: 16 x mfma 16x16x16, P direct from registers
        __builtin_amdgcn_s_setprio(1);
#pragma unroll
        for (int f = 0; f < 4; ++f)
#pragma unroll
            for (int kg = 0; kg < 4; ++kg)
                o[f] = MFMA16(pa[kg], __builtin_bit_cast(s16x4, bv[f][kg]), o[f]);
        __builtin_amdgcn_s_setprio(0);
    }

    // epilogue: l lives per-lane at q=col; reduce across quads, then
    // redistribute to the C-frag rows (q = quad*4+r) via shfl.
    {
        float l = ls;
        l += __shfl_xor(l, 16);
        l += __shfl_xor(l, 32);                   // all quads summed, q=col
        const float linv = (l > 0.f) ? (1.f / l) : 0.f;
#pragma unroll
        for (int r = 0; r < 4; ++r) {
            const float inv = __shfl(linv, quad * 4 + r);   // lane col=quad*4+r
            const int row = q0 + quad * 4 + r;
            float* op = out + obase + (size_t)row * RS;
#pragma unroll
            for (int f = 0; f < 4; ++f)
                op[f * 16 + col] = o[f][r] * inv;
        }
    }
}

extern "C" void kernel_launch(void* const* d_in, const int* in_sizes, int n_in,
                              void* d_out, int out_size, void* d_ws, size_t ws_size,
                              hipStream_t stream) {
    const float* q = (const float*)d_in[0];
    const float* k = (const float*)d_in[1];
    const float* v = (const float*)d_in[2];
    const int* glm = (const int*)d_in[3];
    float* out     = (float*)d_out;

    const size_t kb_bytes = (size_t)KB_ELEMS * 2;            // 8 MB
    __bf16* kbuf = (__bf16*)d_ws;
    __bf16* vbuf = (__bf16*)((char*)d_ws + kb_bytes);

    hipLaunchKernelGGL(conv_kv, dim3(1024), dim3(256), 0, stream,
                       k, v, kbuf, vbuf);
    // 128 q-tiles (LPT order) x 32 heads = 4096 one-wave blocks (16/CU)
    hipLaunchKernelGGL(fa_part16, dim3(4096), dim3(64), 0, stream,
                       q, kbuf, vbuf, glm, out);
}

// Round 16
// 144.879 us; speedup vs baseline: 1.1773x; 1.1773x over previous
//
#include <hip/hip_runtime.h>
#include <hip/hip_bf16.h>

// GLM flash attention fwd: b=2, s=2048, nh=16, hs=64, fp32 I/O, bf16 MFMA.
// R22 = R20 + full chunk-depth pipeline (ONE wait per chunk). R21 proved
// smaller tiles regress (halved compute per chunk, same 24 segments ->
// load:compute doubled; 88.7us). R20's residual 48% idle is its two
// short-cover waits: vmcnt(8) drains V issued only ~300cyc prior (bare L2
// latency). Now K AND V are double-buffered; all 24 loads for chunk c+1
// issue at the top of chunk c; a single s_waitcnt vmcnt(24) (48 in flight
// -> drain the 24 oldest = chunk c's) gives every load a FULL chunk
// (~1500cyc) of cover, and QK->exp->PV runs wait-free. VGPR ~230 <= 256 @
// launch_bounds(64,2); WRITE_SIZE is the spill alarm. Everything else =
// R20 (passed): fragment-tiled kbuf/vbuf (every load one contiguous
// segment), swapped QK^T -> P in registers in MFMA16 A-layout -> PV
// direct, zero LDS, zero barriers, no split-K, no atomics, in-register
// normalize, LPT order, 2048 one-wave blocks.

typedef __attribute__((ext_vector_type(8))) __bf16 bf16x8;
typedef __attribute__((ext_vector_type(4))) __bf16 bf16x4;
typedef __attribute__((ext_vector_type(4))) float floatx4;
typedef __attribute__((ext_vector_type(2))) float f32x2;
typedef __attribute__((ext_vector_type(4))) short s16x4;

#define S_LEN 2048
#define NH 16
#define HS 64
#define RS 1024                     // fp32 floats between seq positions
#define KB_ELEMS (2 * NH * S_LEN * HS)   // 4,194,304 bf16 = 8 MB
#define BH_ELEMS (S_LEN * HS)            // 131072 bf16 per (b,h)
#define SCALE_LOG2E 0.18033688011112042f // 0.125 / ln(2)

#if __has_builtin(__builtin_amdgcn_exp2f)
#define EXP2(x) __builtin_amdgcn_exp2f(x)
#else
#define EXP2(x) exp2f(x)
#endif

#define MFMA(a, b, c) __builtin_amdgcn_mfma_f32_16x16x32_bf16(a, b, c, 0, 0, 0)
// v_mfma_f32_16x16x16_bf16: A/B = 2 VGPRs (4 bf16 as v4i16), C/D = 4 VGPRs
#define MFMA16(a, b, c) __builtin_amdgcn_mfma_f32_16x16x16bf16_1k(a, b, c, 0, 0, 0)

// ---- pre-pass: K -> A-frag tiles (scaled), V -> MFMA16-B-frag tiles ----
// (byte-identical to R20, which passed)
__global__ __launch_bounds__(256) void conv_kv(const float* __restrict__ k,
                                               const float* __restrict__ v,
                                               __bf16* __restrict__ kbuf,
                                               __bf16* __restrict__ vbuf)
{
    __shared__ __align__(16) __bf16 tile[64][72];     // [d][s], 144B rows
    const int tid = threadIdx.x;

    const int bh = blockIdx.x >> 5;                   // 32 s-tiles per (b,h)
    const int st = blockIdx.x & 31;
    const int b = bh >> 4, h = bh & 15;
    const int s0 = st * 64;
    const int kb0 = st * 4;                           // base 16-k block

    __bf16* kout = kbuf + (size_t)(b * 16 + h) * BH_ELEMS;
    __bf16* vout = vbuf + (size_t)(b * 16 + h) * BH_ELEMS;

    // K: read coalesced (32B/thread along rows), write A-frag slots
#pragma unroll
    for (int it = 0; it < 2; ++it) {
        const int idx = it * 256 + tid;               // 0..511
        const int sl = idx >> 3;                      // local k row 0..63
        const int g  = idx & 7;                       // 8-float d-granule
        const float* kp = k + ((size_t)(b * 2048 + s0 + sl)) * 1024 + h * 64 + g * 8;
        floatx4 v0 = *(const floatx4*)kp;
        floatx4 v1 = *(const floatx4*)(kp + 4);
        bf16x8 w;
#pragma unroll
        for (int i = 0; i < 4; ++i) {
            w[i]     = (__bf16)(v0[i] * SCALE_LOG2E);
            w[4 + i] = (__bf16)(v1[i] * SCALE_LOG2E);
        }
        const int kb = kb0 + (sl >> 4);
        const int l  = (g & 3) * 16 + (sl & 15);      // quad=g&3, col=sl&15
        *(bf16x8*)(kout + ((kb * 2 + (g >> 2)) * 512 + l * 8)) = w;
    }

    // V: build [d][s] transpose in LDS (as before)
#pragma unroll
    for (int it = 0; it < 4; ++it) {
        const int idx = it * 256 + tid;
        const int s = idx >> 4, f4 = idx & 15;
        floatx4 val = *(const floatx4*)(v + ((size_t)(b * 2048 + s0 + s)) * 1024 + h * 64 + f4 * 4);
#pragma unroll
        for (int i = 0; i < 4; ++i)
            tile[f4 * 4 + i][s] = (__bf16)val[i];
    }
    __syncthreads();

    // emit B-frag slots (8B/thread, writes fully coalesced per tile)
#pragma unroll
    for (int it = 0; it < 4; ++it) {
        const int idx = it * 256 + tid;               // 0..1023
        const int kbl = idx >> 8;                     // 0..3
        const int f   = (idx >> 6) & 3;
        const int l   = idx & 63;
        const int col = l & 15, q4 = l >> 4;
        bf16x4 w = *(const bf16x4*)&tile[f * 16 + col][kbl * 16 + q4 * 4];
        *(bf16x4*)(vout + (((kb0 + kbl) * 4 + f) * 256 + l * 4)) = w;
    }
}

// ---- main kernel: 1 wave/block, 32 q-rows, all-register, 1 wait/chunk ----
__global__ __launch_bounds__(64, 2) void fa_part17(
    const float* __restrict__ q, const __bf16* __restrict__ kb,
    const __bf16* __restrict__ vt, const int* __restrict__ glm_mask,
    float* __restrict__ out)
{
    const int lane = threadIdx.x;                 // one wave per block
    const int col  = lane & 15, quad = lane >> 4;

    // LPT order: longest q-tiles first (q0 descending), heads fastest
    const int tile = blockIdx.x >> 5;             // 0..63
    const int head = blockIdx.x & 31;
    const int b = head >> 4, h = head & 15;
    const int q0 = (63 - tile) * 32;              // this wave's 32 q-rows

    const int bp = glm_mask[b];
    int klen = q0 + 32; if (bp > klen) klen = bp;
    const int nch = (klen + 63) >> 6;             // 1..32

    const __bf16* kbh = kb + (size_t)(b * 16 + h) * BH_ELEMS;
    const __bf16* vth = vt + (size_t)(b * 16 + h) * BH_ELEMS;
    const size_t obase = (size_t)b * (S_LEN * RS) + h * HS;

    // per-lane slot bases (fully coalesced: lane-linear)
    const char* klp = (const char*)kbh + lane * 16;
    const char* vlp = (const char*)vth + lane * 8;

// K(c) -> DST (8 x 16B volatile asm loads, each ONE 1KB segment)
#define LOADK(DST, K0)                                                         \
  _Pragma("unroll")                                                            \
  for (int kg = 0; kg < 4; ++kg)                                               \
    _Pragma("unroll")                                                          \
    for (int hf = 0; hf < 2; ++hf) {                                           \
      unsigned long long ka = (unsigned long long)(klp +                       \
          (size_t)(K0) * 128 + kg * 2048 + hf * 1024);                         \
      __asm__ __volatile__("global_load_dwordx4 %0, %1, off"                   \
                           : "=v"(DST[kg][hf]) : "v"(ka) : "memory");          \
    }

// V(c) -> DST (16 x 8B volatile asm loads, each ONE 512B segment)
#define LOADV(DST, K0)                                                         \
  _Pragma("unroll")                                                            \
  for (int kg = 0; kg < 4; ++kg)                                               \
    _Pragma("unroll")                                                          \
    for (int f = 0; f < 4; ++f) {                                              \
      unsigned long long va = (unsigned long long)(vlp +                       \
          (size_t)(K0) * 128 + kg * 2048 + f * 512);                           \
      __asm__ __volatile__("global_load_dwordx2 %0, %1, off"                   \
                           : "=v"(DST[f][kg]) : "v"(va) : "memory");           \
    }

    // Q B-frags: aq[rg][half], lane holds Q[q=q0+rg*16+col][d=half*32+quad*8+j]
    bf16x8 aq[2][2];
#pragma unroll
    for (int rg = 0; rg < 2; ++rg) {
        const float* qp = q + obase + (size_t)(q0 + rg * 16 + col) * RS + quad * 8;
        floatx4 a0 = *(const floatx4*)qp;
        floatx4 a1 = *(const floatx4*)(qp + 4);
        floatx4 a2 = *(const floatx4*)(qp + 32);
        floatx4 a3 = *(const floatx4*)(qp + 36);
#pragma unroll
        for (int i = 0; i < 4; ++i) {
            aq[rg][0][i] = (__bf16)a0[i]; aq[rg][0][4 + i] = (__bf16)a1[i];
            aq[rg][1][i] = (__bf16)a2[i]; aq[rg][1][4 + i] = (__bf16)a3[i];
        }
    }

    floatx4 o[2][4];                // O C-frags: row = q0+rg*16+quad*4+r, d = f*16+col
    float ls[2] = {0.f, 0.f};       // per-lane l partial for q = q0+rg*16+col
#pragma unroll
    for (int rg = 0; rg < 2; ++rg)
#pragma unroll
        for (int f = 0; f < 4; ++f)
            o[rg][f] = (floatx4){0.f, 0.f, 0.f, 0.f};

    bf16x8 bkA[4][2], bkB[4][2];    // K double buffer
    f32x2 bvA[4][4], bvB[4][4];     // V double buffer

    LOADK(bkA, 0);                  // prologue: chunk 0 fully in flight
    LOADV(bvA, 0);                  // (24 vm ops)

// One 64-col chunk. BKC/BVC = current buffers, BKN/BVN = next.
// Issue ALL of chunk c+1's loads first, then ONE counted wait for chunk c.
#define CHUNK(C, BKC, BVC, BKN, BVN)                                           \
  {                                                                            \
    const int k0 = (C) * 64;                                                   \
    if ((C) + 1 < nch) {                                                       \
      LOADK(BKN, k0 + 64);                                                     \
      LOADV(BVN, k0 + 64);                                                     \
      /* 48 in flight; drain the 24 oldest = chunk c's */                      \
      __asm__ __volatile__("s_waitcnt vmcnt(24)" ::: "memory");                \
    } else {                                                                   \
      __asm__ __volatile__("s_waitcnt vmcnt(0)" ::: "memory");                 \
    }                                                                          \
    __builtin_amdgcn_sched_barrier(0);                                         \
    /* QK^T swapped: S^T = K . Q^T -> lane holds P[q=col][k=..quad*4+r] */     \
    floatx4 z_ = {0.f, 0.f, 0.f, 0.f};                                         \
    floatx4 s[2][4];                                                           \
    __builtin_amdgcn_s_setprio(1);                                             \
    _Pragma("unroll")                                                          \
    for (int rg = 0; rg < 2; ++rg)                                             \
      _Pragma("unroll")                                                        \
      for (int kg = 0; kg < 4; ++kg) {                                         \
        s[rg][kg] = MFMA(BKC[kg][0], aq[rg][0], z_);                           \
        s[rg][kg] = MFMA(BKC[kg][1], aq[rg][1], s[rg][kg]);                    \
      }                                                                        \
    __builtin_amdgcn_s_setprio(0);                                             \
    /* exp + mask + pack to A-frags of 16x16x16 (all in registers) */          \
    const bool full = (k0 + 63 < bp) || (k0 + 63 <= q0);                       \
    s16x4 pa[2][4];                                                            \
    _Pragma("unroll")                                                          \
    for (int rg = 0; rg < 2; ++rg) {                                           \
      const int qi = q0 + rg * 16 + col;                                       \
      _Pragma("unroll")                                                        \
      for (int kg = 0; kg < 4; ++kg) {                                         \
        bf16x4 pv4;                                                            \
        _Pragma("unroll")                                                      \
        for (int r = 0; r < 4; ++r) {                                          \
          float e = EXP2(s[rg][kg][r]);                                        \
          if (!full) {                                                         \
            const int kj = k0 + kg * 16 + quad * 4 + r;                        \
            if (!((kj < bp) || (kj <= qi))) e = 0.f;                           \
          }                                                                    \
          ls[rg] += e;                                                         \
          pv4[r] = (__bf16)e;                                                  \
        }                                                                      \
        pa[rg][kg] = __builtin_bit_cast(s16x4, pv4);                           \
      }                                                                        \
    }                                                                          \
    /* PV: 32 x mfma 16x16x16, P and V direct from registers, NO wait */      \
    __builtin_amdgcn_s_setprio(1);                                             \
    _Pragma("unroll")                                                          \
    for (int rg = 0; rg < 2; ++rg)                                             \
      _Pragma("unroll")                                                        \
      for (int f = 0; f < 4; ++f)                                              \
        _Pragma("unroll")                                                      \
        for (int kg = 0; kg < 4; ++kg)                                         \
          o[rg][f] = MFMA16(pa[rg][kg],                                        \
                            __builtin_bit_cast(s16x4, BVC[f][kg]), o[rg][f]);  \
    __builtin_amdgcn_s_setprio(0);                                             \
  }

    int c = 0;
    for (; c + 1 < nch; c += 2) {
        CHUNK(c,     bkA, bvA, bkB, bvB);
        CHUNK(c + 1, bkB, bvB, bkA, bvA);
    }
    if (c < nch)
        CHUNK(c, bkA, bvA, bkB, bvB);

    // epilogue: l lives per-lane at q=col; reduce across quads, then
    // redistribute to the C-frag rows (q = quad*4+r) via shfl.
#pragma unroll
    for (int rg = 0; rg < 2; ++rg) {
        float l = ls[rg];
        l += __shfl_xor(l, 16);
        l += __shfl_xor(l, 32);                   // all quads summed, q=rg*16+col
        const float linv = (l > 0.f) ? (1.f / l) : 0.f;
#pragma unroll
        for (int r = 0; r < 4; ++r) {
            const float inv = __shfl(linv, quad * 4 + r);   // lane col=quad*4+r
            const int row = q0 + rg * 16 + quad * 4 + r;
            float* op = out + obase + (size_t)row * RS;
#pragma unroll
            for (int f = 0; f < 4; ++f)
                op[f * 16 + col] = o[rg][f][r] * inv;
        }
    }
}

extern "C" void kernel_launch(void* const* d_in, const int* in_sizes, int n_in,
                              void* d_out, int out_size, void* d_ws, size_t ws_size,
                              hipStream_t stream) {
    const float* q = (const float*)d_in[0];
    const float* k = (const float*)d_in[1];
    const float* v = (const float*)d_in[2];
    const int* glm = (const int*)d_in[3];
    float* out     = (float*)d_out;

    const size_t kb_bytes = (size_t)KB_ELEMS * 2;            // 8 MB
    __bf16* kbuf = (__bf16*)d_ws;
    __bf16* vbuf = (__bf16*)((char*)d_ws + kb_bytes);

    hipLaunchKernelGGL(conv_kv, dim3(1024), dim3(256), 0, stream,
                       k, v, kbuf, vbuf);
    // 64 q-tiles (LPT order) x 32 heads = 2048 one-wave blocks (8/CU)
    hipLaunchKernelGGL(fa_part17, dim3(2048), dim3(64), 0, stream,
                       q, kbuf, vbuf, glm, out);
}